// Round 3
// baseline (49534.634 us; speedup 1.0000x reference)
//
#include <hip/hip_runtime.h>
#include <hip/hip_bf16.h>
#include <math.h>

typedef __hip_bfloat16 bf16;

#define E_DIM 768
#define HEADS 12
#define DHEAD 64
#define LAYERS 12
#define NTOK 197
#define BATCH 64
#define EPSV 1e-5f

__device__ __forceinline__ float b2f(bf16 v) { return __bfloat162float(v); }
__device__ __forceinline__ float ldf(const float* p, long i) { return p[i]; }
__device__ __forceinline__ float ldf(const bf16* p, long i) { return __bfloat162float(p[i]); }
__device__ __forceinline__ void stf(float* p, long i, float v) { p[i] = v; }
__device__ __forceinline__ void stf(bf16* p, long i, float v) { p[i] = __float2bfloat16(v); }

// ---------------- patch embedding: conv(stride=16) + bias + pos ----------------
// grid: (196, imgs), block 256. One block per (patch, local image).
__global__ __launch_bounds__(256) void embed_patches(
    const float* __restrict__ x, const float* __restrict__ cw,
    const float* __restrict__ cb, const float* __restrict__ pos,
    float* __restrict__ h, int b0) {
    int pidx = blockIdx.x;          // 0..195
    int b = blockIdx.y;             // local image index
    int t = threadIdx.x;
    int ph = pidx / 14, pw = pidx % 14;
    __shared__ float patch[768];    // k = c*256 + py*16 + px
    for (int k = t; k < 768; k += 256) {
        int c = k >> 8, r = (k >> 4) & 15, cc = k & 15;
        patch[k] = x[((size_t)((b0 + b) * 3 + c) * 224 + ph * 16 + r) * 224 + pw * 16 + cc];
    }
    __syncthreads();
    int n = pidx + 1;
    for (int e = t; e < 768; e += 256) {
        const float4* w4 = reinterpret_cast<const float4*>(cw + (size_t)e * 768);
        float acc = 0.f;
#pragma unroll 8
        for (int k4 = 0; k4 < 192; ++k4) {
            float4 u = w4[k4];
            int kb = k4 * 4;
            acc += patch[kb + 0] * u.x + patch[kb + 1] * u.y
                 + patch[kb + 2] * u.z + patch[kb + 3] * u.w;
        }
        h[((size_t)b * NTOK + n) * 768 + e] = acc + cb[e] + pos[n * 768 + e];
    }
}

// cls token: h[b][0][e] = cls[e] + pos[0][e].  grid imgs, block 768.
__global__ void embed_cls(const float* __restrict__ cls, const float* __restrict__ pos,
                          float* __restrict__ h) {
    int b = blockIdx.x, e = threadIdx.x;
    h[(size_t)b * NTOK * 768 + e] = cls[e] + pos[e];
}

// ---------------- layernorm over E=768 ----------------
// grid Mr, block 256
__global__ __launch_bounds__(256) void layernorm_k(
    const float* __restrict__ h, float* __restrict__ y,
    const float* __restrict__ s, const float* __restrict__ bsh) {
    int tok = blockIdx.x, t = threadIdx.x;
    const float* row = h + (size_t)tok * 768;
    float v0 = row[t], v1 = row[t + 256], v2 = row[t + 512];
    __shared__ float red[256];
    red[t] = v0 + v1 + v2;
    __syncthreads();
    for (int o = 128; o > 0; o >>= 1) { if (t < o) red[t] += red[t + o]; __syncthreads(); }
    float mean = red[0] * (1.f / 768.f);
    __syncthreads();
    red[t] = v0 * v0 + v1 * v1 + v2 * v2;
    __syncthreads();
    for (int o = 128; o > 0; o >>= 1) { if (t < o) red[t] += red[t + o]; __syncthreads(); }
    float var = red[0] * (1.f / 768.f) - mean * mean;
    float rs = rsqrtf(var + EPSV);
    float* yr = y + (size_t)tok * 768;
    yr[t]       = (v0 - mean) * rs * s[t]       + bsh[t];
    yr[t + 256] = (v1 - mean) * rs * s[t + 256] + bsh[t + 256];
    yr[t + 512] = (v2 - mean) * rs * s[t + 512] + bsh[t + 512];
}

// ---------------- generic fp32-accum GEMM, fp32 weights, A/C dtype templated ----
// C[m, n] = sum_k A[m, k] * W[k, n] (+bias) (+gelu) (+resid),  64x64x16 tiles.
// grid: (N/64, ceil(M/64), batch).  M guarded; N, K must be multiples of 64/16.
#define BM 64
#define BN 64
#define BK 16
template <typename AT, typename CT>
__global__ __launch_bounds__(256) void gemm_t(
    const AT* __restrict__ A, int lda,
    const float* __restrict__ W, int ldw, long wBatchStride,
    const float* __restrict__ bias, int biasBatchStride,
    const float* __restrict__ resid,
    CT* __restrict__ C, int ldc, long cBatchOffset,
    int K, int M, int applyGelu) {
    int bz = blockIdx.z;
    W += (long)bz * wBatchStride;
    if (bias) bias += (long)bz * biasBatchStride;
    C += (long)bz * cBatchOffset;
    int n0 = blockIdx.x * BN, m0 = blockIdx.y * BM;
    int t = threadIdx.x;
    __shared__ float As[BK][BM + 4];
    __shared__ float Ws[BK][BN];
    int tx = t & 15, ty = t >> 4;
    float acc[4][4] = {};
    int a_k = t & 15, a_m0 = t >> 4;   // A loader: 4 rows, stride 16
    int w_n = t & 63, w_k0 = t >> 6;   // W loader: 4 k, stride 4

    for (int k0 = 0; k0 < K; k0 += BK) {
        __syncthreads();
#pragma unroll
        for (int i = 0; i < 4; ++i) {
            int m = a_m0 + i * 16;
            int gm = m0 + m;
            As[a_k][m] = (gm < M) ? ldf(A, (long)gm * lda + k0 + a_k) : 0.f;
        }
#pragma unroll
        for (int i = 0; i < 4; ++i) {
            int k = w_k0 + i * 4;
            Ws[k][w_n] = W[(long)(k0 + k) * ldw + n0 + w_n];
        }
        __syncthreads();
#pragma unroll
        for (int kk = 0; kk < BK; ++kk) {
            float a0 = As[kk][ty * 4 + 0], a1 = As[kk][ty * 4 + 1];
            float a2 = As[kk][ty * 4 + 2], a3 = As[kk][ty * 4 + 3];
            float b0 = Ws[kk][tx * 4 + 0], b1 = Ws[kk][tx * 4 + 1];
            float b2 = Ws[kk][tx * 4 + 2], b3 = Ws[kk][tx * 4 + 3];
            acc[0][0] += a0 * b0; acc[0][1] += a0 * b1; acc[0][2] += a0 * b2; acc[0][3] += a0 * b3;
            acc[1][0] += a1 * b0; acc[1][1] += a1 * b1; acc[1][2] += a1 * b2; acc[1][3] += a1 * b3;
            acc[2][0] += a2 * b0; acc[2][1] += a2 * b1; acc[2][2] += a2 * b2; acc[2][3] += a2 * b3;
            acc[3][0] += a3 * b0; acc[3][1] += a3 * b1; acc[3][2] += a3 * b2; acc[3][3] += a3 * b3;
        }
    }
#pragma unroll
    for (int i = 0; i < 4; ++i) {
        int m = m0 + ty * 4 + i;
        if (m >= M) continue;
#pragma unroll
        for (int j = 0; j < 4; ++j) {
            int n = n0 + tx * 4 + j;
            float v = acc[i][j];
            if (bias) v += bias[n];
            if (applyGelu) v = 0.5f * v * (1.f + erff(v * 0.70710678118f));
            if (resid) v += resid[(long)m * ldc + n];
            stf(C, (long)m * ldc + n, v);
        }
    }
}

// ---------------- fused attention: scores -> softmax -> PV ----------------
// qkv layout (bf16): [Mr, H*192], element (h, 3d+{0,1,2}) = q/k/v
// grid: (25, 12, imgs)   block 256. 8 query rows per block (last tile: 5).
#define ITILE 8
__global__ __launch_bounds__(256) void attn_k(const bf16* __restrict__ qkv,
                                              bf16* __restrict__ att) {
    int it = blockIdx.x, hh = blockIdx.y, b = blockIdx.z;
    int i0 = it * ITILE;
    int nrow = NTOK - i0; if (nrow > ITILE) nrow = ITILE;
    int t = threadIdx.x;
    const bf16* base = qkv + (size_t)b * NTOK * 2304 + hh * 192;

    __shared__ float q[ITILE][DHEAD];
    __shared__ float p[ITILE][NTOK];

    for (int idx = t; idx < ITILE * DHEAD; idx += 256) {
        int i = idx >> 6, d = idx & 63;
        q[i][d] = (i < nrow) ? b2f(base[(long)(i0 + i) * 2304 + 3 * d]) : 0.f;
    }
    __syncthreads();

    if (t < NTOK) {
        const bf16* krow = base + (long)t * 2304 + 1;
        float acc[ITILE] = {};
        for (int d = 0; d < DHEAD; ++d) {
            float kv = b2f(krow[3 * d]);
#pragma unroll
            for (int i = 0; i < ITILE; ++i) acc[i] += q[i][d] * kv;
        }
#pragma unroll
        for (int i = 0; i < ITILE; ++i) p[i][t] = acc[i] * 0.125f;
    }
    __syncthreads();

    // per-row softmax: wave w handles rows w, w+4
    int w = t >> 6, lane = t & 63;
    for (int i = w; i < nrow; i += 4) {
        float m = -1e30f;
        for (int j = lane; j < NTOK; j += 64) m = fmaxf(m, p[i][j]);
        for (int off = 32; off; off >>= 1) m = fmaxf(m, __shfl_xor(m, off));
        float ssum = 0.f;
        for (int j = lane; j < NTOK; j += 64) { float e = __expf(p[i][j] - m); p[i][j] = e; ssum += e; }
        for (int off = 32; off; off >>= 1) ssum += __shfl_xor(ssum, off);
        float inv = 1.f / ssum;
        for (int j = lane; j < NTOK; j += 64) p[i][j] *= inv;
    }
    __syncthreads();

    // PV: thread handles (i = w, w+4; d = lane)
    const bf16* vcol = base + 3 * lane + 2;
    for (int i = w; i < nrow; i += 4) {
        float o = 0.f;
        for (int j = 0; j < NTOK; ++j) o += p[i][j] * b2f(vcol[(long)j * 2304]);
        att[((size_t)b * NTOK + i0 + i) * 768 + hh * 64 + lane] = __float2bfloat16(o);
    }
}

// ---------------- final copy ----------------
__global__ void copy_out(const float* __restrict__ h, float* __restrict__ out, int n) {
    int idx = blockIdx.x * 256 + threadIdx.x;
    if (idx < n) out[idx] = h[idx];
}

extern "C" void kernel_launch(void* const* d_in, const int* in_sizes, int n_in,
                              void* d_out, int out_size, void* d_ws, size_t ws_size,
                              hipStream_t stream) {
    const float* x      = (const float*)d_in[0];
    const float* conv_w = (const float*)d_in[1];
    const float* conv_b = (const float*)d_in[2];
    const float* cls_e  = (const float*)d_in[3];
    const float* pos_e  = (const float*)d_in[4];
    const float* ln1_s  = (const float*)d_in[5];
    const float* ln1_b  = (const float*)d_in[6];
    const float* qkv_w  = (const float*)d_in[7];
    const float* qkv_b  = (const float*)d_in[8];
    const float* proj_w = (const float*)d_in[9];
    const float* proj_b = (const float*)d_in[10];
    const float* ln2_s  = (const float*)d_in[11];
    const float* ln2_b  = (const float*)d_in[12];
    const float* fc1_w  = (const float*)d_in[13];
    const float* fc1_b  = (const float*)d_in[14];
    const float* fc2_w  = (const float*)d_in[15];
    const float* fc2_b  = (const float*)d_in[16];

    // Footprint per chunk of `imgs` images: Mr = imgs*197 rows;
    // h (f32) + y (f32) + att (bf16) + max(qkv bf16, mlp-hidden bf16)
    //   = Mr * (3072 + 3072 + 1536 + 6144) = Mr * 13824 bytes.
    int imgs = BATCH;
    while (imgs > 1 && (size_t)imgs * NTOK * 13824ull > ws_size) imgs >>= 1;
    size_t Mr = (size_t)imgs * NTOK;

    float* h   = (float*)d_ws;
    float* y   = h + Mr * 768;
    bf16*  att = (bf16*)(y + Mr * 768);
    bf16*  big = att + Mr * 768;          // qkv (Mr*2304 bf16) aliased with mlp hidden (Mr*3072 bf16)

    int gy = (int)((Mr + 63) / 64);
    int Mi = (int)Mr;

    for (int b0 = 0; b0 < BATCH; b0 += imgs) {
        embed_patches<<<dim3(196, imgs), 256, 0, stream>>>(x, conv_w, conv_b, pos_e, h, b0);
        embed_cls<<<dim3(imgs), dim3(768), 0, stream>>>(cls_e, pos_e, h);

        for (int l = 0; l < LAYERS; ++l) {
            const float* qw  = qkv_w  + (long)l * HEADS * 768 * 192;
            const float* qb  = qkv_b  + (long)l * HEADS * 192;
            const float* pw  = proj_w + (long)l * 768 * 768;
            const float* pb  = proj_b + (long)l * 768;
            const float* f1w = fc1_w  + (long)l * 768 * 3072;
            const float* f1b = fc1_b  + (long)l * 3072;
            const float* f2w = fc2_w  + (long)l * 3072 * 768;
            const float* f2b = fc2_b  + (long)l * 768;

            layernorm_k<<<Mi, 256, 0, stream>>>(h, y, ln1_s + l * 768, ln1_b + l * 768);
            // qkv: [Mr,768] x [768,192] batched over 12 heads -> bf16 [Mr, 2304]
            gemm_t<float, bf16><<<dim3(3, gy, HEADS), 256, 0, stream>>>(
                y, 768, qw, 192, (long)768 * 192, qb, 192, nullptr,
                big, 2304, 192, 768, Mi, 0);
            attn_k<<<dim3(25, HEADS, imgs), 256, 0, stream>>>(big, att);
            // proj + residual (in-place on h)
            gemm_t<bf16, float><<<dim3(12, gy, 1), 256, 0, stream>>>(
                att, 768, pw, 768, 0, pb, 0, h, h, 768, 0, 768, Mi, 0);
            layernorm_k<<<Mi, 256, 0, stream>>>(h, y, ln2_s + l * 768, ln2_b + l * 768);
            // fc1 + gelu -> bf16 hidden
            gemm_t<float, bf16><<<dim3(48, gy, 1), 256, 0, stream>>>(
                y, 768, f1w, 3072, 0, f1b, 0, nullptr, big, 3072, 0, 768, Mi, 1);
            // fc2 + residual (in-place on h)
            gemm_t<bf16, float><<<dim3(12, gy, 1), 256, 0, stream>>>(
                big, 3072, f2w, 768, 0, f2b, 0, h, h, 768, 0, 3072, Mi, 0);
        }

        int ntot = Mi * 768;
        copy_out<<<(ntot + 255) / 256, 256, 0, stream>>>(
            h, (float*)d_out + (size_t)b0 * NTOK * 768, ntot);
    }
}